// Round 11
// baseline (1080.129 us; speedup 1.0000x reference)
//
#include <hip/hip_runtime.h>
#include <hip/hip_cooperative_groups.h>
#include <cstdint>

namespace cg = cooperative_groups;

#define NN 20000
#define NNP 20096            // 157 * 128, padded row count for all activation buffers
#define NE 640000
#define NEG_SLOPE 0.1f
#define NP4 4                // src partitions (5000 nodes = 2.56 MB table region, L2-sized)
#define PSZ 5000
#define CAP 48               // bucket capacity per (node, partition); occupancy ~Poisson(8)

typedef unsigned short ushort_t;
typedef __attribute__((ext_vector_type(8))) short short8;
typedef __attribute__((ext_vector_type(4))) float f32x4;

__device__ __forceinline__ unsigned short f2bf(float f) {
    union { float f; unsigned u; } v; v.f = f;
    unsigned r = v.u + 0x7fffu + ((v.u >> 16) & 1u);
    return (unsigned short)(r >> 16);
}
__device__ __forceinline__ float bflo(unsigned u) { return __uint_as_float(u << 16); }
__device__ __forceinline__ float bfhi(unsigned u) { return __uint_as_float(u & 0xffff0000u); }

__device__ __forceinline__ int swz(int r) { return (r ^ (r >> 2)) & 3; }

__device__ __forceinline__ void gld_lds16(const void* g, void* l) {
    __builtin_amdgcn_global_load_lds(
        (const __attribute__((address_space(1))) void*)g,
        (__attribute__((address_space(3))) void*)l,
        16, 0, 0);
}

// ---------------- packed Wt region offsets (elements, bf16) ----------------
// All Wt stored as [M][K] row-major (transposed from source [K][M])
#define O_CAT   0            // 384 x 736
#define O_OM    282624       // 384 x 64 (K padded 54->64 with zeros)
#define O_C0    307200       // 128 x 384
#define O_O0    356352       // 128 x 384
#define O_C1    405504       // 128 x 128
#define O_O1    421888
#define O_C2    438272
#define O_O2    454656
#define O_LAT   471040       // 384 x 768
#define O_HEADS 765952       // 256 x 384  (rows 0..127 = drug, 128..255 = dis)
#define WT_TOTAL 864256

#define PACK_TOTAL (WT_TOTAL + 384 + 384 + 256)   // 865280, exact multiple of 256
#define CVT_T1 (NN * 736 / 4)
#define P1_FILLB (NE / 256)                        // 2500 fill blocks (1 edge/lane)
#define P1_CVTB ((CVT_T1 + NN * 64 + 255) / 256)   // convert blocks
#define P1_PKB  (PACK_TOTAL / 256)                 // pack blocks

// ---------------- phase1: bucket-fill ∥ convert_inputs ∥ pack_weights --------
// Round-9 configuration (sequential block order: round-10 permutation was
// time-neutral and raised FETCH 29 MB). One atomic pass builds the bucket
// CSR; convert streams; pack uses the scattered high-TLP gather.
__global__ __launch_bounds__(256) void phase1(
    const int* __restrict__ esrc, const int* __restrict__ edst,
    int* __restrict__ cnt4, unsigned* __restrict__ bkt,
    const float* __restrict__ x, const float* __restrict__ xft,
    ushort_t* __restrict__ xb, ushort_t* __restrict__ xftb,
    const float* __restrict__ Wpe, const float* __restrict__ Wgos, const float* __restrict__ Wprot,
    const float* __restrict__ bpe, const float* __restrict__ bgos, const float* __restrict__ bprot,
    const float* __restrict__ Wom0, const float* __restrict__ Wom1,
    const float* __restrict__ Wom2, const float* __restrict__ Wom3,
    const float* __restrict__ bom0, const float* __restrict__ bom1,
    const float* __restrict__ bom2, const float* __restrict__ bom3,
    const float* __restrict__ Wc0, const float* __restrict__ Wo0,
    const float* __restrict__ Wc1, const float* __restrict__ Wo1,
    const float* __restrict__ Wc2, const float* __restrict__ Wo2,
    const float* __restrict__ Wlat,
    const float* __restrict__ Wdrug, const float* __restrict__ Wdis,
    const float* __restrict__ bdrug, const float* __restrict__ bdis,
    ushort_t* __restrict__ Wt, float* __restrict__ bcat, float* __restrict__ bomc,
    float* __restrict__ bheads)
{
    int bx = blockIdx.x;
    if (bx < P1_FILLB) {
        int e = bx * 256 + threadIdx.x;           // NE == 2500*256 exactly
        int d = edst[e];
        int s = esrc[e];
        int p = (unsigned)s / (unsigned)PSZ;
        int pos = atomicAdd(&cnt4[d * NP4 + p], 1);
        if (pos < CAP)
            bkt[(d * NP4 + p) * CAP + pos] = (unsigned)s * 512u;
        return;
    }
    bx -= P1_FILLB;
    if (bx < P1_CVTB) {
        int i = bx * 256 + threadIdx.x;
        if (i < CVT_T1) {
            int base = i * 4;
            float4 v = *reinterpret_cast<const float4*>(&x[base]);
            unsigned long long p = (unsigned long long)f2bf(v.x)
                                 | ((unsigned long long)f2bf(v.y) << 16)
                                 | ((unsigned long long)f2bf(v.z) << 32)
                                 | ((unsigned long long)f2bf(v.w) << 48);
            *reinterpret_cast<unsigned long long*>(&xb[base]) = p;
            return;
        }
        i -= CVT_T1;
        if (i < NN * 64) {
            int r = i >> 6, c = i & 63;
            float v = (c < 54) ? xft[r * 54 + c] : 0.f;
            xftb[i] = f2bf(v);
        }
        return;
    }
    bx -= P1_CVTB;
    {
        int i = bx * 256 + threadIdx.x;
        if (i < 282624) {                            // WtCat 384 x 736
            int m = i / 736, k = i % 736;
            float v = (k < 128) ? Wpe[k * 384 + m]
                    : (k < 256) ? Wgos[(k - 128) * 384 + m]
                                : Wprot[(k - 256) * 384 + m];
            Wt[O_CAT + i] = f2bf(v);
            return;
        }
        i -= 282624;
        if (i < 24576) {                             // WtOm 384 x 64
            int m = i / 64, k = i % 64;
            float v = (k < 3)  ? Wom0[k * 384 + m]
                    : (k < 6)  ? Wom1[(k - 3) * 384 + m]
                    : (k < 30) ? Wom2[(k - 6) * 384 + m]
                    : (k < 54) ? Wom3[(k - 30) * 384 + m] : 0.f;
            Wt[O_OM + i] = f2bf(v);
            return;
        }
        i -= 24576;
        if (i < 49152) { int m = i / 384, k = i % 384; Wt[O_C0 + i] = f2bf(Wc0[k * 128 + m]); return; }
        i -= 49152;
        if (i < 49152) { int m = i / 384, k = i % 384; Wt[O_O0 + i] = f2bf(Wo0[k * 128 + m]); return; }
        i -= 49152;
        if (i < 16384) { int m = i / 128, k = i % 128; Wt[O_C1 + i] = f2bf(Wc1[k * 128 + m]); return; }
        i -= 16384;
        if (i < 16384) { int m = i / 128, k = i % 128; Wt[O_O1 + i] = f2bf(Wo1[k * 128 + m]); return; }
        i -= 16384;
        if (i < 16384) { int m = i / 128, k = i % 128; Wt[O_C2 + i] = f2bf(Wc2[k * 128 + m]); return; }
        i -= 16384;
        if (i < 16384) { int m = i / 128, k = i % 128; Wt[O_O2 + i] = f2bf(Wo2[k * 128 + m]); return; }
        i -= 16384;
        if (i < 294912) { int m = i / 768, k = i % 768; Wt[O_LAT + i] = f2bf(Wlat[k * 384 + m]); return; }
        i -= 294912;
        if (i < 98304) {                             // heads 256 x 384
            int m = i / 384, k = i % 384;
            float v = (m < 128) ? Wdrug[k * 128 + m] : Wdis[k * 128 + (m - 128)];
            Wt[O_HEADS + i] = f2bf(v);
            return;
        }
        i -= 98304;
        if (i < 384) { bcat[i] = bpe[i] + bgos[i] + bprot[i]; return; }
        i -= 384;
        if (i < 384) { bomc[i] = bom0[i] + bom1[i] + bom2[i] + bom3[i]; return; }
        i -= 384;
        if (i < 256) { bheads[i] = (i < 128) ? bdrug[i] : bdis[i - 128]; return; }
    }
}

// ---------------- bf16 MFMA GEMM core ----------------
template<int BN>
__device__ __forceinline__ void gemm_core(
    ushort_t* As, ushort_t* Bs,
    const ushort_t* __restrict__ A, int lda,
    const ushort_t* __restrict__ Wt, int K, int row0, int col0,
    f32x4 (&acc)[4][(BN == 128) ? 4 : 2])
{
    constexpr int BK = 32;
    constexpr int NI = (BN == 128) ? 4 : 2;

    const int t = threadIdx.x;
    const int w = t >> 6, lane = t & 63;
    const int wr = w >> 1, wc = w & 1;
    const int m16 = lane & 15, quad = lane >> 4;
    const int sr = lane >> 2;       // row within a 16-row staging chunk
    const int pgrp = lane & 3;      // physical 16B group within row

#pragma unroll
    for (int mi = 0; mi < 4; mi++)
#pragma unroll
        for (int ni = 0; ni < NI; ni++) acc[mi][ni] = (f32x4)0.f;

    for (int k0 = 0; k0 < K; k0 += BK) {
#pragma unroll
        for (int p = 0; p < 2; p++) {
            int c = p * 4 + w;
            int r = c * 16 + sr;
            int q = pgrp ^ swz(r);
            gld_lds16(&A[(size_t)(row0 + r) * lda + k0 + q * 8], &As[c * 512]);
        }
#pragma unroll
        for (int p = 0; p < BN / 64; p++) {
            int c = p * 4 + w;
            int r = c * 16 + sr;
            int q = pgrp ^ swz(r);
            gld_lds16(&Wt[(size_t)(col0 + r) * K + k0 + q * 8], &Bs[c * 512]);
        }
        __syncthreads();

        short8 af[4], bfr[NI];
#pragma unroll
        for (int mi = 0; mi < 4; mi++) {
            int r = wr * 64 + mi * 16 + m16;
            int p = quad ^ swz(r);
            af[mi] = *reinterpret_cast<const short8*>(&As[r * 32 + p * 8]);
        }
#pragma unroll
        for (int ni = 0; ni < NI; ni++) {
            int n = wc * (NI * 16) + ni * 16 + m16;
            int p = quad ^ swz(n);
            bfr[ni] = *reinterpret_cast<const short8*>(&Bs[n * 32 + p * 8]);
        }
#pragma unroll
        for (int mi = 0; mi < 4; mi++)
#pragma unroll
            for (int ni = 0; ni < NI; ni++)
                acc[mi][ni] = __builtin_amdgcn_mfma_f32_16x16x32_bf16(af[mi], bfr[ni], acc[mi][ni], 0, 0, 0);
        __syncthreads();
    }
}

template<int BN, bool BIASACT, bool OUT_BF16>
__device__ __forceinline__ void gemm_store(
    const f32x4 (&acc)[4][(BN == 128) ? 4 : 2],
    const float* __restrict__ bias,
    float* __restrict__ Cf, ushort_t* __restrict__ Cb, int ldc,
    int nrows, int row0, int col0)
{
    constexpr int NI = (BN == 128) ? 4 : 2;
    const int t = threadIdx.x;
    const int w = t >> 6, lane = t & 63;
    const int wr = w >> 1, wc = w & 1;
    const int m16 = lane & 15, quad = lane >> 4;
#pragma unroll
    for (int mi = 0; mi < 4; mi++) {
#pragma unroll
        for (int reg = 0; reg < 4; reg++) {
            int grow = row0 + wr * 64 + mi * 16 + quad * 4 + reg;
            if (grow >= nrows) continue;
#pragma unroll
            for (int ni = 0; ni < NI; ni++) {
                int gcol = col0 + wc * (NI * 16) + ni * 16 + m16;
                float v = acc[mi][ni][reg];
                if constexpr (BIASACT) {
                    v += bias[gcol];
                    v = (v > 0.f) ? v : NEG_SLOPE * v;
                }
                if constexpr (OUT_BF16) Cb[(size_t)grow * ldc + gcol] = f2bf(v);
                else                    Cf[(size_t)grow * ldc + gcol] = v;
            }
        }
    }
}

// ---------------- aggregate body (bucket CSR), verbatim round-10 ------------
__device__ __forceinline__ void aggregate_body(
    const ushort_t* __restrict__ tabI,
    const float* __restrict__ bc, const float* __restrict__ bo,
    const int* __restrict__ cnt4, const unsigned* __restrict__ bkt,
    const float* __restrict__ deg_inv,
    ushort_t* __restrict__ outb, int hcol, int gcol, int blk)
{
    const int w = threadIdx.x >> 6, lane = threadIdx.x & 63;
    const int i = blk * 4 + w;                  // node
    const int el = lane >> 5;                   // edge sublane 0..1
    const int fq = lane & 31;                   // 16B-quad across both chains
    const int chain = fq >> 4;
    const unsigned lbyte = (unsigned)(fq * 16);
    const char* __restrict__ tb = (const char*)tabI;

    const float di = deg_inv[i];
    const uint4 pv = *reinterpret_cast<const uint4*>(tb + ((unsigned)i * 512u + lbyte));
    const int4 cc = *reinterpret_cast<const int4*>(&cnt4[i * NP4]);
    const int cn[4] = {cc.x, cc.y, cc.z, cc.w};
    const unsigned* __restrict__ bb = &bkt[(size_t)i * NP4 * CAP];

    float acc[8];
#pragma unroll
    for (int q = 0; q < 8; q++) acc[q] = 0.f;

#define FMA8(P, C) \
    acc[0] = fmaf(bflo(P.x), C, acc[0]); acc[1] = fmaf(bfhi(P.x), C, acc[1]); \
    acc[2] = fmaf(bflo(P.y), C, acc[2]); acc[3] = fmaf(bfhi(P.y), C, acc[3]); \
    acc[4] = fmaf(bflo(P.z), C, acc[4]); acc[5] = fmaf(bfhi(P.z), C, acc[5]); \
    acc[6] = fmaf(bflo(P.w), C, acc[6]); acc[7] = fmaf(bfhi(P.w), C, acc[7])

#pragma unroll
    for (int p = 0; p < NP4; p++) {
        const unsigned* __restrict__ bp = bb + p * CAP;
        const int n = cn[p];
        int j = el;
        for (; j + 6 < n; j += 8) {
            unsigned s0 = bp[j], s1 = bp[j + 2], s2 = bp[j + 4], s3 = bp[j + 6];
            uint4 p0 = *reinterpret_cast<const uint4*>(tb + (s0 + lbyte));
            uint4 p1 = *reinterpret_cast<const uint4*>(tb + (s1 + lbyte));
            uint4 p2 = *reinterpret_cast<const uint4*>(tb + (s2 + lbyte));
            uint4 p3 = *reinterpret_cast<const uint4*>(tb + (s3 + lbyte));
            float c0 = deg_inv[s0 >> 9] * di;
            float c1 = deg_inv[s1 >> 9] * di;
            float c2 = deg_inv[s2 >> 9] * di;
            float c3 = deg_inv[s3 >> 9] * di;
            FMA8(p0, c0); FMA8(p1, c1); FMA8(p2, c2); FMA8(p3, c3);
        }
        if (j < n) {                             // masked tail, <=4 slots
            int l = n - 1;
            unsigned s0 = bp[j];
            unsigned s1 = bp[(j + 2 < n) ? j + 2 : l];
            unsigned s2 = bp[(j + 4 < n) ? j + 4 : l];
            unsigned s3 = bp[(j + 6 < n) ? j + 6 : l];
            uint4 p0 = *reinterpret_cast<const uint4*>(tb + (s0 + lbyte));
            uint4 p1 = *reinterpret_cast<const uint4*>(tb + (s1 + lbyte));
            uint4 p2 = *reinterpret_cast<const uint4*>(tb + (s2 + lbyte));
            uint4 p3 = *reinterpret_cast<const uint4*>(tb + (s3 + lbyte));
            float c0 = deg_inv[s0 >> 9] * di;
            float c1 = (j + 2 < n) ? deg_inv[s1 >> 9] * di : 0.f;
            float c2 = (j + 4 < n) ? deg_inv[s2 >> 9] * di : 0.f;
            float c3 = (j + 6 < n) ? deg_inv[s3 >> 9] * di : 0.f;
            FMA8(p0, c0); FMA8(p1, c1); FMA8(p2, c2); FMA8(p3, c3);
        }
    }
#undef FMA8

#pragma unroll
    for (int q = 0; q < 8; q++) acc[q] += __shfl_xor(acc[q], 32);

    if (el == 0) {
        const float* __restrict__ bias = chain ? bo : bc;
        const int coloff = (fq & 15) * 8;
        const float c = 2.f * di * di;
        float sv[8] = {bflo(pv.x), bfhi(pv.x), bflo(pv.y), bfhi(pv.y),
                       bflo(pv.z), bfhi(pv.z), bflo(pv.w), bfhi(pv.w)};
        uint4 o;
        unsigned* op = &o.x;
#pragma unroll
        for (int q = 0; q < 8; q += 2) {
            float v0 = fmaf(sv[q],     c, acc[q])     + bias[coloff + q];
            float v1 = fmaf(sv[q + 1], c, acc[q + 1]) + bias[coloff + q + 1];
            v0 = (v0 > 0.f) ? v0 : NEG_SLOPE * v0;
            v1 = (v1 > 0.f) ? v1 : NEG_SLOPE * v1;
            op[q >> 1] = (unsigned)f2bf(v0) | ((unsigned)f2bf(v1) << 16);
        }
        const int col = (chain ? gcol : hcol) + coloff;
        *reinterpret_cast<uint4*>(&outb[(size_t)i * 768 + col]) = o;
    }
}

// ---------------- mega: persistent cooperative kernel ----------------------
// Phases separated by grid.sync(): {deginv ∥ input-MLPs} -> 3x{dual GEMM ->
// aggregate} -> latent GEMM -> heads GEMM(+fused 2-wide projection).
// Replaces 8 dispatch boundaries with in-kernel barriers; tmpI/jkb stay
// L2-warm across phases. __launch_bounds__(256,4) caps VGPR at 128 so >=4
// blocks/CU are guaranteed co-resident (grid sized via occupancy API, cap 1280).
struct MegaP {
    const int* cnt4; float* deg_inv;
    const ushort_t* xb; const ushort_t* xftb; const ushort_t* Wt;
    const float* bcat; const float* bomc;
    ushort_t* h0b; ushort_t* g0b;
    ushort_t* jkb; ushort_t* zb; ushort_t* tmpI;
    const unsigned* bkt;
    const float* bc0; const float* bo0;
    const float* bc1; const float* bo1;
    const float* bc2; const float* bo2;
    const float* b_lat; const float* bheads;
    const float* Wod; const float* bod;
    const float* Wos; const float* bos;
    float* out;
};

#define MD_DGB 79
#define MD_MLPB (3 * 157 * 2)

__global__ __launch_bounds__(256, 4) void mega(MegaP P)
{
    cg::grid_group grid = cg::this_grid();
    __shared__ ushort_t As[128 * 32];
    __shared__ ushort_t Bs[128 * 32];
    const int NB = (int)gridDim.x;

    // ---- phase A: deginv ∥ input MLPs ----
    for (int it = blockIdx.x; it < MD_DGB + MD_MLPB; it += NB) {
        if (it < MD_DGB) {
            int i = it * 256 + threadIdx.x;
            if (i < NN) {
                int4 c = *reinterpret_cast<const int4*>(&P.cnt4[i * NP4]);
                P.deg_inv[i] = rsqrtf((float)(c.x + c.y + c.z + c.w) + 2.0f);
            }
            continue;
        }
        int b = it - MD_DGB;
        int z = b / 471, r = b % 471;
        int by = r / 3, b3 = r % 3;
        f32x4 acc[4][4];
        const int row0 = by * 128, col0 = b3 * 128;
        if (z == 0) {
            gemm_core<128>(As, Bs, P.xb, 736, P.Wt + O_CAT, 736, row0, col0, acc);
            gemm_store<128, true, true>(acc, P.bcat, nullptr, P.h0b, 384, NN, row0, col0);
        } else {
            gemm_core<128>(As, Bs, P.xftb, 64, P.Wt + O_OM, 64, row0, col0, acc);
            gemm_store<128, true, true>(acc, P.bomc, nullptr, P.g0b, 384, NN, row0, col0);
        }
    }
    grid.sync();

    // ---- 3 GCN layers: dual GEMM -> sync -> aggregate -> sync ----
    const ushort_t* dA0[3] = {P.h0b, P.jkb + 0,   P.jkb + 128};
    const ushort_t* dA1[3] = {P.g0b, P.jkb + 384, P.jkb + 512};
    const int dlda[3] = {384, 768, 768};
    const int dK[3]   = {384, 128, 128};
    const int dW0[3]  = {O_C0, O_C1, O_C2};
    const int dW1[3]  = {O_O0, O_O1, O_O2};
    const float* abc[3] = {P.bc0, P.bc1, P.bc2};
    const float* abo[3] = {P.bo0, P.bo1, P.bo2};
    const int hcolA[3] = {0, 128, 256};
    const int gcolA[3] = {384, 512, 640};

#pragma unroll 1
    for (int L = 0; L < 3; L++) {
        for (int it = blockIdx.x; it < 2 * 157 * 2; it += NB) {
            int z = it & 1, rr = it >> 1;       // rr in [0, 314)
            int bxx = rr & 1, by = rr >> 1;     // by in [0, 157)
            const ushort_t* A  = z ? dA1[L] : dA0[L];
            const ushort_t* W  = P.Wt + (z ? dW1[L] : dW0[L]);
            ushort_t*       Cb = P.tmpI + z * 128;
            f32x4 acc[4][2];
            gemm_core<64>(As, Bs, A, dlda[L], W, dK[L], by * 128, bxx * 64, acc);
            gemm_store<64, false, true>(acc, nullptr, nullptr, Cb, 256, NN,
                                        by * 128, bxx * 64);
        }
        grid.sync();
        for (int it = blockIdx.x; it < NN / 4; it += NB) {
            aggregate_body(P.tmpI, abc[L], abo[L], P.cnt4, P.bkt, P.deg_inv,
                           P.jkb, hcolA[L], gcolA[L], it);
        }
        grid.sync();
    }

    // ---- latent GEMM ----
    for (int it = blockIdx.x; it < 3 * 157; it += NB) {
        int b3 = it % 3, by = it / 3;
        f32x4 acc[4][4];
        gemm_core<128>(As, Bs, P.jkb, 768, P.Wt + O_LAT, 768, by * 128, b3 * 128, acc);
        gemm_store<128, true, true>(acc, P.b_lat, nullptr, P.zb, 384, NN, by * 128, b3 * 128);
    }
    grid.sync();

    // ---- heads GEMM + fused 2-wide projection ----
    for (int it = blockIdx.x; it < 2 * 157; it += NB) {
        int cx = it & 1, by = it >> 1;
        const int row0 = by * 128, col0 = cx * 128;
        f32x4 acc[4][4];
        gemm_core<128>(As, Bs, P.zb, 384, P.Wt + O_HEADS, 384, row0, col0, acc);

        const float* __restrict__ Wh = col0 ? P.Wos : P.Wod;
        const float* __restrict__ bh = col0 ? P.bos : P.bod;
        const int t = threadIdx.x;
        const int w = t >> 6, lane = t & 63;
        const int wr = w >> 1, wc = w & 1;
        const int m16 = lane & 15, quad = lane >> 4;

        float w0[4], w1[4];
#pragma unroll
        for (int ni = 0; ni < 4; ni++) {
            int k = wc * 64 + ni * 16 + m16;
            w0[ni] = Wh[k * 2 + 0];
            w1[ni] = Wh[k * 2 + 1];
        }
        float p0[16], p1[16];
#pragma unroll
        for (int mi = 0; mi < 4; mi++) {
#pragma unroll
            for (int reg = 0; reg < 4; reg++) {
                float s0 = 0.f, s1 = 0.f;
#pragma unroll
                for (int ni = 0; ni < 4; ni++) {
                    int gcol = col0 + wc * 64 + ni * 16 + m16;
                    float v = acc[mi][ni][reg] + P.bheads[gcol];
                    v = (v > 0.f) ? v : NEG_SLOPE * v;
                    s0 = fmaf(v, w0[ni], s0);
                    s1 = fmaf(v, w1[ni], s1);
                }
                p0[mi * 4 + reg] = s0;
                p1[mi * 4 + reg] = s1;
            }
        }
#pragma unroll
        for (int m = 1; m <= 8; m <<= 1) {
#pragma unroll
            for (int idx = 0; idx < 16; idx++) {
                p0[idx] += __shfl_xor(p0[idx], m);
                p1[idx] += __shfl_xor(p1[idx], m);
            }
        }
        float* red = reinterpret_cast<float*>(As);     // gemm_core ended with sync
        if (m16 == 0) {
#pragma unroll
            for (int mi = 0; mi < 4; mi++)
#pragma unroll
                for (int reg = 0; reg < 4; reg++) {
                    int row = mi * 16 + quad * 4 + reg;
                    int base = (((wr * 2 + wc) * 64) + row) * 2;
                    red[base + 0] = p0[mi * 4 + reg];
                    red[base + 1] = p1[mi * 4 + reg];
                }
        }
        __syncthreads();
        if (t < 128) {
            int wr2 = t >> 6, row = t & 63;
            int grow = row0 + wr2 * 64 + row;
            if (grow < NN) {
                int b0 = ((wr2 * 2 + 0) * 64 + row) * 2;
                int b1 = ((wr2 * 2 + 1) * 64 + row) * 2;
                float o0 = red[b0 + 0] + red[b1 + 0] + bh[0];
                float o1 = red[b0 + 1] + red[b1 + 1] + bh[1];
                P.out[(size_t)grow * 4 + (col0 ? 2 : 0) + 0] = o0;
                P.out[(size_t)grow * 4 + (col0 ? 2 : 0) + 1] = o1;
            }
        }
        __syncthreads();                               // protect As before next iter
    }
}

// ---------------- launch ----------------
extern "C" void kernel_launch(void* const* d_in, const int* in_sizes, int n_in,
                              void* d_out, int out_size, void* d_ws, size_t ws_size,
                              hipStream_t stream)
{
    const float* x      = (const float*)d_in[0];
    const float* x_ft   = (const float*)d_in[1];
    const int*   eidx   = (const int*)d_in[2];
    const float* W_pe   = (const float*)d_in[3];
    const float* b_pe   = (const float*)d_in[4];
    const float* W_gos  = (const float*)d_in[5];
    const float* b_gos  = (const float*)d_in[6];
    const float* W_prot = (const float*)d_in[7];
    const float* b_prot = (const float*)d_in[8];
    const float* W_om0  = (const float*)d_in[9];
    const float* b_om0  = (const float*)d_in[10];
    const float* W_om1  = (const float*)d_in[11];
    const float* b_om1  = (const float*)d_in[12];
    const float* W_om2  = (const float*)d_in[13];
    const float* b_om2  = (const float*)d_in[14];
    const float* W_om3  = (const float*)d_in[15];
    const float* b_om3  = (const float*)d_in[16];
    const float* W_c[3] = {(const float*)d_in[17], (const float*)d_in[21], (const float*)d_in[25]};
    const float* b_c[3] = {(const float*)d_in[18], (const float*)d_in[22], (const float*)d_in[26]};
    const float* W_o[3] = {(const float*)d_in[19], (const float*)d_in[23], (const float*)d_in[27]};
    const float* b_o[3] = {(const float*)d_in[20], (const float*)d_in[24], (const float*)d_in[28]};
    const float* W_lat  = (const float*)d_in[29];
    const float* b_lat  = (const float*)d_in[30];
    const float* W_drug = (const float*)d_in[31];
    const float* b_drug = (const float*)d_in[32];
    const float* W_dis  = (const float*)d_in[33];
    const float* b_dis  = (const float*)d_in[34];
    const float* W_odrug= (const float*)d_in[35];
    const float* b_odrug= (const float*)d_in[36];
    const float* W_odis = (const float*)d_in[37];
    const float* b_odis = (const float*)d_in[38];
    float* out = (float*)d_out;

    const int* e_src = eidx;
    const int* e_dst = eidx + NE;

    char* p = (char*)d_ws;
    auto alloc = [&](size_t bytes) -> void* {
        void* r = (void*)p;
        p += (bytes + 255) & ~(size_t)255;
        return r;
    };
    ushort_t* Wt    = (ushort_t*)alloc((size_t)WT_TOTAL * 2);
    float* bcat     = (float*)alloc(384 * 4);
    float* bomc     = (float*)alloc(384 * 4);
    float* bheads   = (float*)alloc(256 * 4);
    float* deg_inv  = (float*)alloc((size_t)NN * 4);
    int*   cnt4     = (int*)alloc((size_t)NN * NP4 * 4);
    unsigned* bkt   = (unsigned*)alloc((size_t)NN * NP4 * CAP * 4);
    ushort_t* xb    = (ushort_t*)alloc((size_t)NNP * 736 * 2);
    ushort_t* xftb  = (ushort_t*)alloc((size_t)NNP * 64 * 2);
    ushort_t* h0b   = (ushort_t*)alloc((size_t)NNP * 384 * 2);
    ushort_t* g0b   = (ushort_t*)alloc((size_t)NNP * 384 * 2);
    ushort_t* jkb   = (ushort_t*)alloc((size_t)NNP * 768 * 2);
    ushort_t* zb    = (ushort_t*)alloc((size_t)NNP * 384 * 2);
    ushort_t* tmpI  = (ushort_t*)alloc((size_t)NNP * 256 * 2);
    (void)ws_size; (void)in_sizes; (void)n_in; (void)out_size;

    // 1. zero bucket counters, then fused front-end (fill ∥ convert ∥ pack)
    hipMemsetAsync(cnt4, 0, (size_t)NN * NP4 * 4, stream);
    phase1<<<dim3(P1_FILLB + P1_CVTB + P1_PKB), dim3(256), 0, stream>>>(
        e_src, e_dst, cnt4, bkt,
        x, x_ft, xb, xftb,
        W_pe, W_gos, W_prot, b_pe, b_gos, b_prot,
        W_om0, W_om1, W_om2, W_om3, b_om0, b_om1, b_om2, b_om3,
        W_c[0], W_o[0], W_c[1], W_o[1], W_c[2], W_o[2],
        W_lat, W_drug, W_dis, b_drug, b_dis, Wt, bcat, bomc, bheads);

    // 2. persistent cooperative kernel: the entire remaining pipeline.
    MegaP ma;
    ma.cnt4 = cnt4; ma.deg_inv = deg_inv;
    ma.xb = xb; ma.xftb = xftb; ma.Wt = Wt;
    ma.bcat = bcat; ma.bomc = bomc;
    ma.h0b = h0b; ma.g0b = g0b;
    ma.jkb = jkb; ma.zb = zb; ma.tmpI = tmpI;
    ma.bkt = bkt;
    ma.bc0 = b_c[0]; ma.bo0 = b_o[0];
    ma.bc1 = b_c[1]; ma.bo1 = b_o[1];
    ma.bc2 = b_c[2]; ma.bo2 = b_o[2];
    ma.b_lat = b_lat; ma.bheads = bheads;
    ma.Wod = W_odrug; ma.bod = b_odrug;
    ma.Wos = W_odis;  ma.bos = b_odis;
    ma.out = out;

    int nbPerCU = 0;
    if (hipOccupancyMaxActiveBlocksPerMultiprocessor(&nbPerCU, mega, 256, 0)
            != hipSuccess || nbPerCU < 1)
        nbPerCU = 2;                                   // conservative fallback
    int nblk = nbPerCU * 256;                          // 256 CUs on MI355X
    if (nblk > 1280) nblk = 1280;

    void* kargs[] = { (void*)&ma };
    hipLaunchCooperativeKernel(mega, dim3(nblk), dim3(256), kargs, 0, stream);
}

// Round 12
// 429.150 us; speedup vs baseline: 2.5169x; 2.5169x over previous
//
#include <hip/hip_runtime.h>
#include <cstdint>

#define NN 20000
#define NNP 20096            // 157 * 128, padded row count for all activation buffers
#define NE 640000
#define NEG_SLOPE 0.1f
#define NP4 4                // src partitions (5000 nodes = 2.56 MB table region, L2-sized)
#define PSZ 5000
#define CAP 48               // bucket capacity per (node, partition); occupancy ~Poisson(8)

typedef unsigned short ushort_t;
typedef __attribute__((ext_vector_type(8))) short short8;
typedef __attribute__((ext_vector_type(4))) float f32x4;

__device__ __forceinline__ unsigned short f2bf(float f) {
    union { float f; unsigned u; } v; v.f = f;
    unsigned r = v.u + 0x7fffu + ((v.u >> 16) & 1u);
    return (unsigned short)(r >> 16);
}
__device__ __forceinline__ float bflo(unsigned u) { return __uint_as_float(u << 16); }
__device__ __forceinline__ float bfhi(unsigned u) { return __uint_as_float(u & 0xffff0000u); }

__device__ __forceinline__ int swz(int r) { return (r ^ (r >> 2)) & 3; }

__device__ __forceinline__ void gld_lds16(const void* g, void* l) {
    __builtin_amdgcn_global_load_lds(
        (const __attribute__((address_space(1))) void*)g,
        (__attribute__((address_space(3))) void*)l,
        16, 0, 0);
}

// ---------------- packed Wt region offsets (elements, bf16) ----------------
// All Wt stored as [M][K] row-major (transposed from source [K][M])
#define O_CAT   0            // 384 x 736
#define O_OM    282624       // 384 x 64 (K padded 54->64 with zeros)
#define O_C0    307200       // 128 x 384
#define O_O0    356352       // 128 x 384
#define O_C1    405504       // 128 x 128
#define O_O1    421888
#define O_C2    438272
#define O_O2    454656
#define O_LAT   471040       // 384 x 768
#define O_HEADS 765952       // 256 x 384  (rows 0..127 = drug, 128..255 = dis)
#define WT_TOTAL 864256

#define PACK_TOTAL (WT_TOTAL + 384 + 384 + 256)   // 865280, exact multiple of 256
#define CVT_T1 (NN * 736 / 4)
#define P1_FILLB (NE / 256)                        // 2500 fill blocks (1 edge/lane)
#define P1_CVTB ((CVT_T1 + NN * 64 + 255) / 256)   // convert blocks
#define P1_PKB  (PACK_TOTAL / 256)                 // pack blocks

// ---------------- phase1: bucket-fill ∥ convert_inputs ∥ pack_weights --------
// Measured-best round-9 configuration. One atomic pass builds the bucket CSR;
// convert streams; pack uses the scattered high-TLP gather (round-8 lesson:
// tiled transpose lost; round-10 lesson: block permutation null on time).
// cnt4 zeroed beforehand (memset).
__global__ __launch_bounds__(256) void phase1(
    const int* __restrict__ esrc, const int* __restrict__ edst,
    int* __restrict__ cnt4, unsigned* __restrict__ bkt,
    const float* __restrict__ x, const float* __restrict__ xft,
    ushort_t* __restrict__ xb, ushort_t* __restrict__ xftb,
    const float* __restrict__ Wpe, const float* __restrict__ Wgos, const float* __restrict__ Wprot,
    const float* __restrict__ bpe, const float* __restrict__ bgos, const float* __restrict__ bprot,
    const float* __restrict__ Wom0, const float* __restrict__ Wom1,
    const float* __restrict__ Wom2, const float* __restrict__ Wom3,
    const float* __restrict__ bom0, const float* __restrict__ bom1,
    const float* __restrict__ bom2, const float* __restrict__ bom3,
    const float* __restrict__ Wc0, const float* __restrict__ Wo0,
    const float* __restrict__ Wc1, const float* __restrict__ Wo1,
    const float* __restrict__ Wc2, const float* __restrict__ Wo2,
    const float* __restrict__ Wlat,
    const float* __restrict__ Wdrug, const float* __restrict__ Wdis,
    const float* __restrict__ bdrug, const float* __restrict__ bdis,
    ushort_t* __restrict__ Wt, float* __restrict__ bcat, float* __restrict__ bomc,
    float* __restrict__ bheads)
{
    int bx = blockIdx.x;
    if (bx < P1_FILLB) {
        // ---- bucket fill: one edge per lane, one atomic ----
        int e = bx * 256 + threadIdx.x;           // NE == 2500*256 exactly
        int d = edst[e];
        int s = esrc[e];
        int p = (unsigned)s / (unsigned)PSZ;
        int pos = atomicAdd(&cnt4[d * NP4 + p], 1);
        if (pos < CAP)                            // statistically impossible overflow guard
            bkt[(d * NP4 + p) * CAP + pos] = (unsigned)s * 512u;  // byte offset of table row
        return;
    }
    bx -= P1_FILLB;
    if (bx < P1_CVTB) {
        // ---- input conversion ----
        int i = bx * 256 + threadIdx.x;
        if (i < CVT_T1) {
            int base = i * 4;
            float4 v = *reinterpret_cast<const float4*>(&x[base]);
            unsigned long long p = (unsigned long long)f2bf(v.x)
                                 | ((unsigned long long)f2bf(v.y) << 16)
                                 | ((unsigned long long)f2bf(v.z) << 32)
                                 | ((unsigned long long)f2bf(v.w) << 48);
            *reinterpret_cast<unsigned long long*>(&xb[base]) = p;
            return;
        }
        i -= CVT_T1;
        if (i < NN * 64) {
            int r = i >> 6, c = i & 63;
            float v = (c < 54) ? xft[r * 54 + c] : 0.f;
            xftb[i] = f2bf(v);
        }
        return;
    }
    bx -= P1_CVTB;
    {
        // ---- weight pack (scattered gather, high-TLP) ----
        int i = bx * 256 + threadIdx.x;
        if (i < 282624) {                            // WtCat 384 x 736
            int m = i / 736, k = i % 736;
            float v = (k < 128) ? Wpe[k * 384 + m]
                    : (k < 256) ? Wgos[(k - 128) * 384 + m]
                                : Wprot[(k - 256) * 384 + m];
            Wt[O_CAT + i] = f2bf(v);
            return;
        }
        i -= 282624;
        if (i < 24576) {                             // WtOm 384 x 64
            int m = i / 64, k = i % 64;
            float v = (k < 3)  ? Wom0[k * 384 + m]
                    : (k < 6)  ? Wom1[(k - 3) * 384 + m]
                    : (k < 30) ? Wom2[(k - 6) * 384 + m]
                    : (k < 54) ? Wom3[(k - 30) * 384 + m] : 0.f;
            Wt[O_OM + i] = f2bf(v);
            return;
        }
        i -= 24576;
        if (i < 49152) { int m = i / 384, k = i % 384; Wt[O_C0 + i] = f2bf(Wc0[k * 128 + m]); return; }
        i -= 49152;
        if (i < 49152) { int m = i / 384, k = i % 384; Wt[O_O0 + i] = f2bf(Wo0[k * 128 + m]); return; }
        i -= 49152;
        if (i < 16384) { int m = i / 128, k = i % 128; Wt[O_C1 + i] = f2bf(Wc1[k * 128 + m]); return; }
        i -= 16384;
        if (i < 16384) { int m = i / 128, k = i % 128; Wt[O_O1 + i] = f2bf(Wo1[k * 128 + m]); return; }
        i -= 16384;
        if (i < 16384) { int m = i / 128, k = i % 128; Wt[O_C2 + i] = f2bf(Wc2[k * 128 + m]); return; }
        i -= 16384;
        if (i < 16384) { int m = i / 128, k = i % 128; Wt[O_O2 + i] = f2bf(Wo2[k * 128 + m]); return; }
        i -= 16384;
        if (i < 294912) { int m = i / 768, k = i % 768; Wt[O_LAT + i] = f2bf(Wlat[k * 384 + m]); return; }
        i -= 294912;
        if (i < 98304) {                             // heads 256 x 384
            int m = i / 384, k = i % 384;
            float v = (m < 128) ? Wdrug[k * 128 + m] : Wdis[k * 128 + (m - 128)];
            Wt[O_HEADS + i] = f2bf(v);
            return;
        }
        i -= 98304;
        if (i < 384) { bcat[i] = bpe[i] + bgos[i] + bprot[i]; return; }
        i -= 384;
        if (i < 384) { bomc[i] = bom0[i] + bom1[i] + bom2[i] + bom3[i]; return; }
        i -= 384;
        if (i < 256) { bheads[i] = (i < 128) ? bdrug[i] : bdis[i - 128]; return; }
    }
}

// ---------------- bf16 MFMA GEMM core ----------------
// acc = A(bf16, rows row0.., lda) @ Wt(bf16, [M][K])^T tile. BM=128, BK=32,
// 256 threads = 4 waves 2x2.
template<int BN>
__device__ __forceinline__ void gemm_core(
    ushort_t* As, ushort_t* Bs,
    const ushort_t* __restrict__ A, int lda,
    const ushort_t* __restrict__ Wt, int K, int row0, int col0,
    f32x4 (&acc)[4][(BN == 128) ? 4 : 2])
{
    constexpr int BK = 32;
    constexpr int NI = (BN == 128) ? 4 : 2;

    const int t = threadIdx.x;
    const int w = t >> 6, lane = t & 63;
    const int wr = w >> 1, wc = w & 1;
    const int m16 = lane & 15, quad = lane >> 4;
    const int sr = lane >> 2;       // row within a 16-row staging chunk
    const int pgrp = lane & 3;      // physical 16B group within row

#pragma unroll
    for (int mi = 0; mi < 4; mi++)
#pragma unroll
        for (int ni = 0; ni < NI; ni++) acc[mi][ni] = (f32x4)0.f;

    for (int k0 = 0; k0 < K; k0 += BK) {
#pragma unroll
        for (int p = 0; p < 2; p++) {
            int c = p * 4 + w;
            int r = c * 16 + sr;
            int q = pgrp ^ swz(r);
            gld_lds16(&A[(size_t)(row0 + r) * lda + k0 + q * 8], &As[c * 512]);
        }
#pragma unroll
        for (int p = 0; p < BN / 64; p++) {
            int c = p * 4 + w;
            int r = c * 16 + sr;
            int q = pgrp ^ swz(r);
            gld_lds16(&Wt[(size_t)(col0 + r) * K + k0 + q * 8], &Bs[c * 512]);
        }
        __syncthreads();

        short8 af[4], bfr[NI];
#pragma unroll
        for (int mi = 0; mi < 4; mi++) {
            int r = wr * 64 + mi * 16 + m16;
            int p = quad ^ swz(r);
            af[mi] = *reinterpret_cast<const short8*>(&As[r * 32 + p * 8]);
        }
#pragma unroll
        for (int ni = 0; ni < NI; ni++) {
            int n = wc * (NI * 16) + ni * 16 + m16;
            int p = quad ^ swz(n);
            bfr[ni] = *reinterpret_cast<const short8*>(&Bs[n * 32 + p * 8]);
        }
#pragma unroll
        for (int mi = 0; mi < 4; mi++)
#pragma unroll
            for (int ni = 0; ni < NI; ni++)
                acc[mi][ni] = __builtin_amdgcn_mfma_f32_16x16x32_bf16(af[mi], bfr[ni], acc[mi][ni], 0, 0, 0);
        __syncthreads();
    }
}

// standard epilogue: C/D layout col=lane&15, row=quad*4+reg
template<int BN, bool BIASACT, bool OUT_BF16>
__device__ __forceinline__ void gemm_store(
    const f32x4 (&acc)[4][(BN == 128) ? 4 : 2],
    const float* __restrict__ bias,
    float* __restrict__ Cf, ushort_t* __restrict__ Cb, int ldc,
    int nrows, int row0, int col0)
{
    constexpr int NI = (BN == 128) ? 4 : 2;
    const int t = threadIdx.x;
    const int w = t >> 6, lane = t & 63;
    const int wr = w >> 1, wc = w & 1;
    const int m16 = lane & 15, quad = lane >> 4;
#pragma unroll
    for (int mi = 0; mi < 4; mi++) {
#pragma unroll
        for (int reg = 0; reg < 4; reg++) {
            int grow = row0 + wr * 64 + mi * 16 + quad * 4 + reg;
            if (grow >= nrows) continue;
#pragma unroll
            for (int ni = 0; ni < NI; ni++) {
                int gcol = col0 + wc * (NI * 16) + ni * 16 + m16;
                float v = acc[mi][ni][reg];
                if constexpr (BIASACT) {
                    v += bias[gcol];
                    v = (v > 0.f) ? v : NEG_SLOPE * v;
                }
                if constexpr (OUT_BF16) Cb[(size_t)grow * ldc + gcol] = f2bf(v);
                else                    Cf[(size_t)grow * ldc + gcol] = v;
            }
        }
    }
}

template<int BN, bool BIASACT, bool OUT_BF16>
__global__ __launch_bounds__(256) void mfma_gemm(
    const ushort_t* __restrict__ A, int lda,
    const ushort_t* __restrict__ Wt,
    const float* __restrict__ bias,
    float* __restrict__ Cf, ushort_t* __restrict__ Cb, int ldc,
    int nrows, int K)
{
    __shared__ ushort_t As[128 * 32];
    __shared__ ushort_t Bs[BN * 32];
    f32x4 acc[4][(BN == 128) ? 4 : 2];
    gemm_core<BN>(As, Bs, A, lda, Wt, K, blockIdx.y * 128, blockIdx.x * BN, acc);
    gemm_store<BN, BIASACT, OUT_BF16>(acc, bias, Cf, Cb, ldc, nrows,
                                      blockIdx.y * 128, blockIdx.x * BN);
}

// ---------------- mlp + deginv in one launch (1D grid) ----------------
// deginv (79 lean blocks, first) ∥ input MLPs (942 GEMM blocks: z=0 cat
// K=736, z=1 om K=64). deginv's consumer (aggregate L0) is two dispatches
// later, so its blocks just need to run sometime during this launch.
#define MD_DGB 79
#define MD_MLPB (3 * 157 * 2)
__global__ __launch_bounds__(256) void mlp_deginv(
    const int* __restrict__ cnt4, float* __restrict__ deg_inv,
    const ushort_t* __restrict__ xb, const ushort_t* __restrict__ xftb,
    const ushort_t* __restrict__ Wt,
    const float* __restrict__ bcat, const float* __restrict__ bomc,
    ushort_t* __restrict__ h0b, ushort_t* __restrict__ g0b)
{
    __shared__ ushort_t As[128 * 32];
    __shared__ ushort_t Bs[128 * 32];
    int bx = blockIdx.x;
    if (bx < MD_DGB) {
        int i = bx * 256 + threadIdx.x;
        if (i < NN) {
            int4 c = *reinterpret_cast<const int4*>(&cnt4[i * NP4]);
            deg_inv[i] = rsqrtf((float)(c.x + c.y + c.z + c.w) + 2.0f);
        }
        return;
    }
    bx -= MD_DGB;
    int z = bx / 471, r = bx % 471;
    int by = r / 3, b3 = r % 3;
    f32x4 acc[4][4];
    const int row0 = by * 128, col0 = b3 * 128;
    if (z == 0) {
        gemm_core<128>(As, Bs, xb, 736, Wt + O_CAT, 736, row0, col0, acc);
        gemm_store<128, true, true>(acc, bcat, nullptr, h0b, 384, NN, row0, col0);
    } else {
        gemm_core<128>(As, Bs, xftb, 64, Wt + O_OM, 64, row0, col0, acc);
        gemm_store<128, true, true>(acc, bomc, nullptr, g0b, 384, NN, row0, col0);
    }
}

// z-batched dual GEMM, BN=64, no bias, bf16 out into the INTERLEAVED tmp table:
// row i = [chainA 128 feats | chainB 128 feats], ldc=256.
__global__ __launch_bounds__(256) void mfma_gemm_dual(
    const ushort_t* __restrict__ A0, const ushort_t* __restrict__ A1, int lda,
    const ushort_t* __restrict__ W0, const ushort_t* __restrict__ W1,
    ushort_t* __restrict__ tmpI,
    int nrows, int K)
{
    __shared__ ushort_t As[128 * 32];
    __shared__ ushort_t Bs[64 * 32];
    const ushort_t* A  = blockIdx.z ? A1 : A0;
    const ushort_t* Wt = blockIdx.z ? W1 : W0;
    ushort_t*       Cb = tmpI + blockIdx.z * 128;
    f32x4 acc[4][2];
    gemm_core<64>(As, Bs, A, lda, Wt, K, blockIdx.y * 128, blockIdx.x * 64, acc);
    gemm_store<64, false, true>(acc, nullptr, nullptr, Cb, 256, nrows,
                                blockIdx.y * 128, blockIdx.x * 64);
}

// heads GEMM with FUSED final 2-wide projection (see round-3 comment).
__global__ __launch_bounds__(256) void mfma_gemm_heads(
    const ushort_t* __restrict__ zb, const ushort_t* __restrict__ Wt,
    const float* __restrict__ bheads,
    const float* __restrict__ Wod, const float* __restrict__ bod,
    const float* __restrict__ Wos, const float* __restrict__ bos,
    float* __restrict__ out)
{
    __shared__ ushort_t As[128 * 32];
    __shared__ ushort_t Bs[128 * 32];
    f32x4 acc[4][4];
    const int row0 = blockIdx.y * 128, col0 = blockIdx.x * 128;
    gemm_core<128>(As, Bs, zb, 384, Wt + O_HEADS, 384, row0, col0, acc);

    const float* __restrict__ Wh = col0 ? Wos : Wod;   // [128][2] row-major
    const float* __restrict__ bh = col0 ? bos : bod;
    const int t = threadIdx.x;
    const int w = t >> 6, lane = t & 63;
    const int wr = w >> 1, wc = w & 1;
    const int m16 = lane & 15, quad = lane >> 4;

    float w0[4], w1[4];
#pragma unroll
    for (int ni = 0; ni < 4; ni++) {
        int k = wc * 64 + ni * 16 + m16;               // local feature index
        w0[ni] = Wh[k * 2 + 0];
        w1[ni] = Wh[k * 2 + 1];
    }
    float p0[16], p1[16];
#pragma unroll
    for (int mi = 0; mi < 4; mi++) {
#pragma unroll
        for (int reg = 0; reg < 4; reg++) {
            float s0 = 0.f, s1 = 0.f;
#pragma unroll
            for (int ni = 0; ni < 4; ni++) {
                int gcol = col0 + wc * 64 + ni * 16 + m16;
                float v = acc[mi][ni][reg] + bheads[gcol];
                v = (v > 0.f) ? v : NEG_SLOPE * v;
                s0 = fmaf(v, w0[ni], s0);
                s1 = fmaf(v, w1[ni], s1);
            }
            p0[mi * 4 + reg] = s0;
            p1[mi * 4 + reg] = s1;
        }
    }
#pragma unroll
    for (int m = 1; m <= 8; m <<= 1) {
#pragma unroll
        for (int idx = 0; idx < 16; idx++) {
            p0[idx] += __shfl_xor(p0[idx], m);
            p1[idx] += __shfl_xor(p1[idx], m);
        }
    }
    float* red = reinterpret_cast<float*>(As);         // [wr][wc][row64][2]
    if (m16 == 0) {
#pragma unroll
        for (int mi = 0; mi < 4; mi++)
#pragma unroll
            for (int reg = 0; reg < 4; reg++) {
                int row = mi * 16 + quad * 4 + reg;
                int base = (((wr * 2 + wc) * 64) + row) * 2;
                red[base + 0] = p0[mi * 4 + reg];
                red[base + 1] = p1[mi * 4 + reg];
            }
    }
    __syncthreads();
    if (t < 128) {
        int wr2 = t >> 6, row = t & 63;
        int grow = row0 + wr2 * 64 + row;
        if (grow < NN) {
            int b0 = ((wr2 * 2 + 0) * 64 + row) * 2;
            int b1 = ((wr2 * 2 + 1) * 64 + row) * 2;
            float o0 = red[b0 + 0] + red[b1 + 0] + bh[0];
            float o1 = red[b0 + 1] + red[b1 + 1] + bh[1];
            out[(size_t)grow * 4 + (col0 ? 2 : 0) + 0] = o0;
            out[(size_t)grow * 4 + (col0 ? 2 : 0) + 1] = o1;
        }
    }
}

// ---------------- GCN aggregation: wave per node, bucket CSR ----------------
// 4 sub-lists per node (one per src partition) -> gathers iterate 2.56 MB
// L2-sized table regions in order. coef computed on the fly from deg_inv
// (80 KB, cache-resident). Masked tails per sub-list.
__global__ __launch_bounds__(256) void aggregate_fused(
    const ushort_t* __restrict__ tabI,
    const float* __restrict__ bc, const float* __restrict__ bo,
    const int* __restrict__ cnt4, const unsigned* __restrict__ bkt,
    const float* __restrict__ deg_inv,
    ushort_t* __restrict__ outb, int hcol, int gcol)
{
    const int w = threadIdx.x >> 6, lane = threadIdx.x & 63;
    const int i = blockIdx.x * 4 + w;           // node (grid = NN/4 exactly)
    const int el = lane >> 5;                   // edge sublane 0..1
    const int fq = lane & 31;                   // 16B-quad across both chains
    const int chain = fq >> 4;
    const unsigned lbyte = (unsigned)(fq * 16);
    const char* __restrict__ tb = (const char*)tabI;

    const float di = deg_inv[i];
    const uint4 pv = *reinterpret_cast<const uint4*>(tb + ((unsigned)i * 512u + lbyte));
    const int4 cc = *reinterpret_cast<const int4*>(&cnt4[i * NP4]);
    const int cn[4] = {cc.x, cc.y, cc.z, cc.w};
    const unsigned* __restrict__ bb = &bkt[(size_t)i * NP4 * CAP];

    float acc[8];
#pragma unroll
    for (int q = 0; q < 8; q++) acc[q] = 0.f;

#define FMA8(P, C) \
    acc[0] = fmaf(bflo(P.x), C, acc[0]); acc[1] = fmaf(bfhi(P.x), C, acc[1]); \
    acc[2] = fmaf(bflo(P.y), C, acc[2]); acc[3] = fmaf(bfhi(P.y), C, acc[3]); \
    acc[4] = fmaf(bflo(P.z), C, acc[4]); acc[5] = fmaf(bfhi(P.z), C, acc[5]); \
    acc[6] = fmaf(bflo(P.w), C, acc[6]); acc[7] = fmaf(bfhi(P.w), C, acc[7])

#pragma unroll
    for (int p = 0; p < NP4; p++) {
        const unsigned* __restrict__ bp = bb + p * CAP;
        const int n = cn[p];
        int j = el;
        for (; j + 6 < n; j += 8) {
            unsigned s0 = bp[j], s1 = bp[j + 2], s2 = bp[j + 4], s3 = bp[j + 6];
            uint4 p0 = *reinterpret_cast<const uint4*>(tb + (s0 + lbyte));
            uint4 p1 = *reinterpret_cast<const uint4*>(tb + (s1 + lbyte));
            uint4 p2 = *reinterpret_cast<const uint4*>(tb + (s2 + lbyte));
            uint4 p3 = *reinterpret_cast<const uint4*>(tb + (s3 + lbyte));
            float c0 = deg_inv[s0 >> 9] * di;
            float c1 = deg_inv[s1 >> 9] * di;
            float c2 = deg_inv[s2 >> 9] * di;
            float c3 = deg_inv[s3 >> 9] * di;
            FMA8(p0, c0); FMA8(p1, c1); FMA8(p2, c2); FMA8(p3, c3);
        }
        if (j < n) {                             // masked tail, <=4 slots
            int l = n - 1;
            unsigned s0 = bp[j];
            unsigned s1 = bp[(j + 2 < n) ? j + 2 : l];
            unsigned s2 = bp[(j + 4 < n) ? j + 4 : l];
            unsigned s3 = bp[(j + 6 < n) ? j + 6 : l];
            uint4 p0 = *reinterpret_cast<const uint4*>(tb + (s0 + lbyte));
            uint4 p1 = *reinterpret_cast<const uint4*>(tb + (s1 + lbyte));
            uint4 p2 = *reinterpret_cast<const uint4*>(tb + (s2 + lbyte));
            uint4 p3 = *reinterpret_cast<const uint4*>(tb + (s3 + lbyte));
            float c0 = deg_inv[s0 >> 9] * di;
            float c1 = (j + 2 < n) ? deg_inv[s1 >> 9] * di : 0.f;
            float c2 = (j + 4 < n) ? deg_inv[s2 >> 9] * di : 0.f;
            float c3 = (j + 6 < n) ? deg_inv[s3 >> 9] * di : 0.f;
            FMA8(p0, c0); FMA8(p1, c1); FMA8(p2, c2); FMA8(p3, c3);
        }
    }
#undef FMA8

#pragma unroll
    for (int q = 0; q < 8; q++) acc[q] += __shfl_xor(acc[q], 32);

    if (el == 0) {
        const float* __restrict__ bias = chain ? bo : bc;
        const int coloff = (fq & 15) * 8;
        const float c = 2.f * di * di;
        float sv[8] = {bflo(pv.x), bfhi(pv.x), bflo(pv.y), bfhi(pv.y),
                       bflo(pv.z), bfhi(pv.z), bflo(pv.w), bfhi(pv.w)};
        uint4 o;
        unsigned* op = &o.x;
#pragma unroll
        for (int q = 0; q < 8; q += 2) {
            float v0 = fmaf(sv[q],     c, acc[q])     + bias[coloff + q];
            float v1 = fmaf(sv[q + 1], c, acc[q + 1]) + bias[coloff + q + 1];
            v0 = (v0 > 0.f) ? v0 : NEG_SLOPE * v0;
            v1 = (v1 > 0.f) ? v1 : NEG_SLOPE * v1;
            op[q >> 1] = (unsigned)f2bf(v0) | ((unsigned)f2bf(v1) << 16);
        }
        const int col = (chain ? gcol : hcol) + coloff;
        *reinterpret_cast<uint4*>(&outb[(size_t)i * 768 + col]) = o;
    }
}

// ---------------- launch ----------------
extern "C" void kernel_launch(void* const* d_in, const int* in_sizes, int n_in,
                              void* d_out, int out_size, void* d_ws, size_t ws_size,
                              hipStream_t stream)
{
    const float* x      = (const float*)d_in[0];
    const float* x_ft   = (const float*)d_in[1];
    const int*   eidx   = (const int*)d_in[2];
    const float* W_pe   = (const float*)d_in[3];
    const float* b_pe   = (const float*)d_in[4];
    const float* W_gos  = (const float*)d_in[5];
    const float* b_gos  = (const float*)d_in[6];
    const float* W_prot = (const float*)d_in[7];
    const float* b_prot = (const float*)d_in[8];
    const float* W_om0  = (const float*)d_in[9];
    const float* b_om0  = (const float*)d_in[10];
    const float* W_om1  = (const float*)d_in[11];
    const float* b_om1  = (const float*)d_in[12];
    const float* W_om2  = (const float*)d_in[13];
    const float* b_om2  = (const float*)d_in[14];
    const float* W_om3  = (const float*)d_in[15];
    const float* b_om3  = (const float*)d_in[16];
    const float* W_c[3] = {(const float*)d_in[17], (const float*)d_in[21], (const float*)d_in[25]};
    const float* b_c[3] = {(const float*)d_in[18], (const float*)d_in[22], (const float*)d_in[26]};
    const float* W_o[3] = {(const float*)d_in[19], (const float*)d_in[23], (const float*)d_in[27]};
    const float* b_o[3] = {(const float*)d_in[20], (const float*)d_in[24], (const float*)d_in[28]};
    const float* W_lat  = (const float*)d_in[29];
    const float* b_lat  = (const float*)d_in[30];
    const float* W_drug = (const float*)d_in[31];
    const float* b_drug = (const float*)d_in[32];
    const float* W_dis  = (const float*)d_in[33];
    const float* b_dis  = (const float*)d_in[34];
    const float* W_odrug= (const float*)d_in[35];
    const float* b_odrug= (const float*)d_in[36];
    const float* W_odis = (const float*)d_in[37];
    const float* b_odis = (const float*)d_in[38];
    float* out = (float*)d_out;

    const int* e_src = eidx;
    const int* e_dst = eidx + NE;

    char* p = (char*)d_ws;
    auto alloc = [&](size_t bytes) -> void* {
        void* r = (void*)p;
        p += (bytes + 255) & ~(size_t)255;
        return r;
    };
    ushort_t* Wt    = (ushort_t*)alloc((size_t)WT_TOTAL * 2);
    float* bcat     = (float*)alloc(384 * 4);
    float* bomc     = (float*)alloc(384 * 4);
    float* bheads   = (float*)alloc(256 * 4);
    float* deg_inv  = (float*)alloc((size_t)NN * 4);
    int*   cnt4     = (int*)alloc((size_t)NN * NP4 * 4);
    unsigned* bkt   = (unsigned*)alloc((size_t)NN * NP4 * CAP * 4);
    ushort_t* xb    = (ushort_t*)alloc((size_t)NNP * 736 * 2);
    ushort_t* xftb  = (ushort_t*)alloc((size_t)NNP * 64 * 2);
    ushort_t* h0b   = (ushort_t*)alloc((size_t)NNP * 384 * 2);
    ushort_t* g0b   = (ushort_t*)alloc((size_t)NNP * 384 * 2);
    ushort_t* jkb   = (ushort_t*)alloc((size_t)NNP * 768 * 2);
    ushort_t* zb    = (ushort_t*)alloc((size_t)NNP * 384 * 2);
    ushort_t* tmpI  = (ushort_t*)alloc((size_t)NNP * 256 * 2);
    (void)ws_size; (void)in_sizes; (void)n_in; (void)out_size;

    // 1. zero bucket counters, then fused front-end (fill ∥ convert ∥ pack)
    hipMemsetAsync(cnt4, 0, (size_t)NN * NP4 * 4, stream);
    phase1<<<dim3(P1_FILLB + P1_CVTB + P1_PKB), dim3(256), 0, stream>>>(
        e_src, e_dst, cnt4, bkt,
        x, x_ft, xb, xftb,
        W_pe, W_gos, W_prot, b_pe, b_gos, b_prot,
        W_om0, W_om1, W_om2, W_om3, b_om0, b_om1, b_om2, b_om3,
        W_c[0], W_o[0], W_c[1], W_o[1], W_c[2], W_o[2],
        W_lat, W_drug, W_dis, b_drug, b_dis, Wt, bcat, bomc, bheads);

    // 2. deginv ∥ input MLPs (one launch)
    mlp_deginv<<<dim3(MD_DGB + MD_MLPB), dim3(256), 0, stream>>>(
        cnt4, deg_inv, xb, xftb, Wt, bcat, bomc, h0b, g0b);

    // 3. three GCN layers. jkb = bf16 [h1 h2 h3 g1 g2 g3], stride 768
    mfma_gemm_dual<<<dim3(2, 157, 2), dim3(256), 0, stream>>>(
        h0b, g0b, 384, Wt + O_C0, Wt + O_O0, tmpI, NN, 384);
    aggregate_fused<<<dim3(NN / 4), dim3(256), 0, stream>>>(
        tmpI, b_c[0], b_o[0], cnt4, bkt, deg_inv, jkb, 0, 384);

    mfma_gemm_dual<<<dim3(2, 157, 2), dim3(256), 0, stream>>>(
        jkb + 0, jkb + 384, 768, Wt + O_C1, Wt + O_O1, tmpI, NN, 128);
    aggregate_fused<<<dim3(NN / 4), dim3(256), 0, stream>>>(
        tmpI, b_c[1], b_o[1], cnt4, bkt, deg_inv, jkb, 128, 512);

    mfma_gemm_dual<<<dim3(2, 157, 2), dim3(256), 0, stream>>>(
        jkb + 128, jkb + 512, 768, Wt + O_C2, Wt + O_O2, tmpI, NN, 128);
    aggregate_fused<<<dim3(NN / 4), dim3(256), 0, stream>>>(
        tmpI, b_c[2], b_o[2], cnt4, bkt, deg_inv, jkb, 256, 640);

    // 4. latent: zb = act(jkb @ W_lat + b_lat), bf16
    mfma_gemm<128, true, true><<<dim3(3, 157), dim3(256), 0, stream>>>(
        jkb, 768, Wt + O_LAT, b_lat, nullptr, zb, 384, NN, 768);

    // 5. heads GEMM with fused 2-wide projection -> out
    mfma_gemm_heads<<<dim3(2, 157), dim3(256), 0, stream>>>(
        zb, Wt, bheads, W_odrug, b_odrug, W_odis, b_odis, out);
}